// Round 15
// baseline (196.134 us; speedup 1.0000x reference)
//
#include <hip/hip_runtime.h>
#include <math.h>

typedef _Float16 f16;
typedef _Float16 half4 __attribute__((ext_vector_type(4)));
typedef _Float16 half8 __attribute__((ext_vector_type(8)));
typedef float f32x4  __attribute__((ext_vector_type(4)));
typedef float f32x16 __attribute__((ext_vector_type(16)));

#define DEV __device__ __forceinline__

// ---------------- workspace layout (bytes) ----------------
#define W1F_OFF 0        // [L][nt2]      : 16 frags  = 16 KB   (x 2*log2e)
#define W2F_OFF 16384    // [L][kt4][nt2] : 64 frags  = 64 KB   (unscaled)
#define WOF_OFF 81920    // [L][u8][kt4]  : 256 frags = 256 KB  (x log2e)
#define B1T_OFF 344064   // [L][nt2][khi2][16] f32 b1 ROW-vec (x 2*log2e) = 2 KB
#define B2T_OFF 346112   // [L][nt2][khi2][16] f32 b2 ROW-vec (unscaled)  = 2 KB
#define SUMLOG_OFF 352256 // 1 fp32: sum over all layers/features of log|scale|
#define W0F_OFF 352320   // [L][64] half8 A-frags of W0^T (mask-zeroed, x 2*log2e) = 8 KB
#define B0T_OFF 361088   // [L][khi2][16] f32 b0 ROW-vec (x 2*log2e) = 1 KB
#define BOT_OFF 363136   // [L][u8][khi2][16] f32 bout ROW-vec (x log2e, offset folded) = 8 KB

// ---------------- LDS: PER-WAVE ARENA (7168 B), 4 waves/block --------------
// 32 SAMPLES PER WAVE (r15): each sample is owned by a khi-pair of lanes
// (ln31, khi=0/1); all MFMA tiles are single 32-sample tiles (the old mt
// dimension is gone). Total waves = B/32 = 4096 -> 4 waves/SIMD (was 2):
// the kernel is latency-bound (58% VALUBusy, ~40% idle issue), so doubled
// TLP is the lever. Per-wave work halves; z is replicated in both khi
// lanes and kept in sync with one __shfl_xor per feature-pair.
// Arena regions (wave-private; per-wave DS program order makes P alias
// H0+H safely: a2 reads precede P stores; next layer's H0 writes follow
// the last P read):
//   H0 : [32][48]  f16 h0 staging     @ arena+0     (1536)
//   H  : [32][152] f16 h1/h2 staging  @ arena+1536  (4864, ends 6400)
//   P  : 2 slots x [32][112] f32      @ arena+0     (7168; bytes 6400..7168
//        are P-only tail)
// Do NOT raise __launch_bounds__ waves/EU above 2 ((256,4) r1/r2 and
// (256,3) r9 spilled f32x16 blocks); residency comes naturally from
// VGPR<=128 + LDS 28672/block + grid B/128 = 4 blocks/CU.
#define H0_OFF    0
#define H0_STRIDE 48
#define H_OFF     1536
#define H_STRIDE  152
#define P_OFF     0
#define P_STRIDE  112
#define P_SLOT    3584
#define ARENA     7168
#define LDS_BYTES (4 * ARENA)   // 28672

DEV float frcp(float x){ return __builtin_amdgcn_rcpf(x); }

#if __has_builtin(__builtin_amdgcn_exp2f)
DEV float fexp2(float x){ return __builtin_amdgcn_exp2f(x); }
#else
DEV float fexp2(float x){ return exp2f(x); }
#endif
#if __has_builtin(__builtin_amdgcn_logf)
DEV float flog2(float x){ return __builtin_amdgcn_logf(x); }
#else
DEV float flog2(float x){ return log2f(x); }
#endif

#define LN2F    0.69314718056f
#define LOG2EF  1.4426950409f
#define TWOLOG2EF 2.8853900818f

// tanh with PRE-SCALED input: x' = 2*log2e * x_linear.
// tanh = 1 - 2/(2^{x'}+1). Robust without clamp. 4 instructions.
DEV float ftanh2(float x){
  float e = fexp2(x);
  float r = frcp(e + 1.f);
  return fmaf(-2.f, r, 1.f);
}

// Rational-quadratic spline forward + log-det (fp32, per-thread).
// p in LOG2 DOMAIN (params x log2e, softplus offset pre-folded at prep).
// ld_out in LOG2 units.
DEV void rq_spline(const float p[25], float xv, float &y_out, float &ld_out)
{
  float ew[8]; float sw = 0.f;
#pragma unroll
  for (int k = 0; k < 8; ++k){ ew[k] = fexp2(p[k]); sw += ew[k]; }
  float rw = frcp(sw) * 19.9992f;           // (RMAX-RMIN) - K*MIN_BIN

  float xpos[9];
  xpos[0] = -10.f;
#pragma unroll
  for (int k = 0; k < 8; ++k) xpos[k + 1] = xpos[k] + fmaf(ew[k], rw, 1e-4f);

  bool b[8];
  int idx = 0;
#pragma unroll
  for (int j = 1; j < 8; ++j){ b[j] = (xv >= xpos[j]); idx += b[j] ? 1 : 0; }

  float xk = xpos[0], ewk = ew[0];
#pragma unroll
  for (int j = 1; j < 8; ++j){
    xk  = b[j] ? xpos[j] : xk;
    ewk = b[j] ? ew[j]   : ewk;
  }
  float bw = fmaf(ewk, rw, 1e-4f);

  float eh[8]; float shs = 0.f;
#pragma unroll
  for (int k = 0; k < 8; ++k){ eh[k] = fexp2(p[8 + k]); shs += eh[k]; }
  float rh = frcp(shs) * 19.9992f;

  float S = 0.f, ehk = eh[0];
#pragma unroll
  for (int k = 1; k < 8; ++k){
    S   += b[k] ? eh[k - 1] : 0.f;
    ehk  = b[k] ? eh[k]     : ehk;
  }
  float yk = fmaf(S, rh, fmaf((float)idx, 1e-4f, -10.f));
  float bh = fmaf(ehk, rh, 1e-4f);

  float vA = p[16], vB = p[17];
#pragma unroll
  for (int j = 1; j < 8; ++j){
    vA = b[j] ? p[16 + j] : vA;
    vB = b[j] ? p[17 + j] : vB;
  }
  // softplus in log2 domain: ln(1+e^u) = ln2*(max(v,0)+log2(1+2^{-|v|}))
  float tA = fmaxf(vA, 0.f) + flog2(1.f + fexp2(-fabsf(vA)));
  float dk  = fmaf(LN2F, tA, 1e-4f);
  float tB = fmaxf(vB, 0.f) + flog2(1.f + fexp2(-fabsf(vB)));
  float dk1 = fmaf(LN2F, tB, 1e-4f);

  float rbw = frcp(bw);
  float s   = bh * rbw;
  float zf  = fminf(fmaxf((xv - xk) * rbw, 0.f), 1.f);
  float z1  = 1.f - zf;
  float zz  = zf * zf, z01 = zf * z1;
  float den = s + (dk1 + dk - 2.f * s) * z01;
  float rden = frcp(den);
  float yv  = yk + bh * (s * zz + dk * z01) * rden;
  float num = dk1 * zz + 2.f * s * z01 + dk * z1 * z1;
  float ldv2 = flog2(s * s * num * rden * rden);   // log2-domain

  bool outside = (xv <= -10.f) || (xv >= 10.f);
  y_out  = outside ? xv : yv;
  ld_out = outside ? 0.f : ldv2;
}

// ---------------- prep kernel: pack fp16 fragments into ws ----------------
// (byte-identical to r13 — all fragment formats unchanged)
extern "C" __global__ void __launch_bounds__(256)
prep_kernel(const float* __restrict__ W0, const float* __restrict__ b0,
            const float* __restrict__ W1, const float* __restrict__ b1,
            const float* __restrict__ W2, const float* __restrict__ b2,
            const float* __restrict__ Wo, const float* __restrict__ bout,
            const float* __restrict__ scale, char* __restrict__ ws)
{
  int tid = blockIdx.x * 256 + threadIdx.x;
  if (tid < 1024){                       // W1 frags: [L][nt2]  (x 2*log2e)
    int fi = tid >> 6, lane = tid & 63;
    int l = fi >> 1, nt = fi & 1;
    int n = nt * 32 + (lane & 31), khi = lane >> 5;
    half8 h;
#pragma unroll
    for (int j = 0; j < 8; ++j){ int k = khi * 8 + j; h[j] = (f16)(W1[l * 1024 + k * 64 + n] * TWOLOG2EF); }
    *(half8*)(ws + W1F_OFF + fi * 1024 + lane * 16) = h;
  } else if (tid < 5120){                // W2 frags: [L][kt4][nt2] (unscaled)
    int idx = tid - 1024;
    int fi = idx >> 6, lane = idx & 63;
    int l = fi >> 3, kt = (fi >> 1) & 3, nt = fi & 1;
    int n = nt * 32 + (lane & 31), khi = lane >> 5;
    half8 h;
#pragma unroll
    for (int j = 0; j < 8; ++j){ int k = kt * 16 + khi * 8 + j; h[j] = (f16)W2[l * 4096 + k * 64 + n]; }
    *(half8*)(ws + W2F_OFF + fi * 1024 + lane * 16) = h;
  } else if (tid < 21504){               // Wout used-col frags: [L][u8][kt4] (x log2e)
    int idx = tid - 5120;
    int fi = idx >> 6, lane = idx & 63;
    int l = fi >> 5, u = (fi >> 2) & 7, kt = fi & 3;
    int f = (l & 1) + 2 * u;
    int c = lane & 31, khi = lane >> 5;
    half8 h;
#pragma unroll
    for (int j = 0; j < 8; ++j){
      int k = kt * 16 + khi * 8 + j;
      float v = (c < 25) ? Wo[l * 25600 + k * 400 + f * 25 + c] * LOG2EF : 0.f;
      h[j] = (f16)v;
    }
    *(half8*)(ws + WOF_OFF + fi * 1024 + lane * 16) = h;
  } else if (tid < 22016){               // B1T row-bias: 512 floats (x 2*log2e)
    int idx = tid - 21504;               // = ((l*2+nt)*2+kh)*16 + i
    int l = idx >> 6, nt = (idx >> 5) & 1, kh = (idx >> 4) & 1, i = idx & 15;
    int r = (i & 3) + 8 * (i >> 2) + 4 * kh;
    ((float*)(ws + B1T_OFF))[idx] = b1[l * 64 + nt * 32 + r] * TWOLOG2EF;
  } else if (tid < 22528){               // B2T row-bias: 512 floats (unscaled)
    int idx = tid - 22016;
    int l = idx >> 6, nt = (idx >> 5) & 1, kh = (idx >> 4) & 1, i = idx & 15;
    int r = (i & 3) + 8 * (i >> 2) + 4 * kh;
    ((float*)(ws + B2T_OFF))[idx] = b2[l * 64 + nt * 32 + r];
  } else if (tid == 23552){              // sum of log|scale| over all layers
    float acc = 0.f;
    for (int i = 0; i < 128; ++i) acc += logf(fabsf(scale[i]));
    *(float*)(ws + SUMLOG_OFF) = acc;
  } else if (tid > 23552 && tid < 24065){ // W0F frags: [L], 512 threads
    int idx = tid - 23553;               // = l*64 + lane
    int l = idx >> 6, lane = idx & 63;
    int n = lane & 31, kh5 = lane >> 5;
    half8 h;
#pragma unroll
    for (int j = 0; j < 8; ++j){
      int k = kh5 * 8 + j;
      float v = 0.f;
      if (n < 16 && (((k + l) & 1) == 1))
        v = W0[l * 256 + k * 16 + n] * TWOLOG2EF;
      h[j] = (f16)v;
    }
    *(half8*)(ws + W0F_OFF + idx * 16) = h;
  } else if (tid >= 24065 && tid < 24321){ // B0T row-bias: 256 floats
    int idx = tid - 24065;               // = (l*2+kh)*16 + i
    int l = idx >> 5, kh = (idx >> 4) & 1, i = idx & 15;
    int r = (i & 3) + 8 * (i >> 2) + 4 * kh;
    float v = (r < 16) ? b0[l * 16 + r] * TWOLOG2EF : 0.f;
    ((float*)(ws + B0T_OFF))[idx] = v;
  } else if (tid >= 26241 && tid < 28289){ // BOT row-bias: 2048 floats
    int idx = tid - 26241;               // = l*256 + u*32 + khi*16 + i
    int l = idx >> 8, u = (idx >> 5) & 7, kh = (idx >> 4) & 1, i = idx & 15;
    int f = (l & 1) + 2 * u;
    int r = (i & 3) + 8 * (i >> 2) + 4 * kh;
    float v = 0.f;
    if (r < 25){
      v = bout[l * 400 + f * 25 + r];
      if (r >= 16) v += 0.54116666f;     // softplus offset folded
      v *= LOG2EF;
    }
    ((float*)(ws + BOT_OFF))[idx] = v;
  }
}

// ---- load a 16-float row-bias vector (BOT layout) ----
DEV void load_botv(const char* __restrict__ ws, int l, int u, int khi,
                   float (&botv)[16])
{
  const f32x4* bp = (const f32x4*)(ws + BOT_OFF) + ((l * 8 + u) * 2 + khi) * 4;
  f32x4 q0 = bp[0], q1 = bp[1], q2 = bp[2], q3 = bp[3];
#pragma unroll
  for (int i = 0; i < 4; ++i){
    botv[i] = q0[i]; botv[4 + i] = q1[i]; botv[8 + i] = q2[i]; botv[12 + i] = q3[i];
  }
}

// ---- H b128-equivalent load split into two b64s (stride 152 rows are only
//      8B-aligned; b64 at 38-dword stride is 2-way = free). ----
DEV half8 ld_h8_pair(const char* p)
{
  half4 lo = *(const half4*)(p);
  half4 hi = *(const half4*)(p + 8);
  half8 r;
#pragma unroll
  for (int i = 0; i < 4; ++i){ r[i] = lo[i]; r[4 + i] = hi[i]; }
  return r;
}

// ---- one Wout feature-PAIR: two swapped MFMAs (features uA, uB) into the
// two P slots. Lane stores rows r(i,khi) of both features; the khi pair
// jointly fills all 25 rows of each slot.
DEV void wout_pair(const half8 (&a2)[4],
                   const half8 (&bfnA)[4], const half8 (&bfnB)[4],
                   const float (&botvA)[16], const float (&botvB)[16],
                   char* ldsw, int ln31, int khi)
{
  f32x16 dpA, dpB;
#pragma unroll
  for (int i = 0; i < 16; ++i){ dpA[i] = botvA[i]; dpB[i] = botvB[i]; }
#pragma unroll
  for (int kt = 0; kt < 4; ++kt){
    dpA = __builtin_amdgcn_mfma_f32_32x32x16_f16(bfnA[kt], a2[kt], dpA, 0, 0, 0);
    dpB = __builtin_amdgcn_mfma_f32_32x32x16_f16(bfnB[kt], a2[kt], dpB, 0, 0, 0);
  }
#pragma unroll
  for (int sl = 0; sl < 2; ++sl){
    const f32x16 &dp = sl ? dpB : dpA;
    char* base = ldsw + P_OFF + sl * P_SLOT + ln31 * P_STRIDE + khi * 16;
    f32x4 c0, c1, c2;
#pragma unroll
    for (int i = 0; i < 4; ++i){
      c0[i] = dp[i];       // params r = 4*khi + 0..3
      c1[i] = dp[4 + i];   // params r = 4*khi + 8..11
      c2[i] = dp[8 + i];   // params r = 4*khi + 16..19
    }
    *(f32x4*)(base)      = c0;
    *(f32x4*)(base + 32) = c1;
    *(f32x4*)(base + 64) = c2;
    if (khi == 0)                                  // r = 24
      *(float*)(base + 96) = dp[12];
  }
}

// ---------------- one coupling layer: 32 samples/wave, 2 lanes/sample ------
// All four GEMMs use the swapped MFMA (D^T = W^T . h^T) on a SINGLE
// 32-sample tile. Lane (ln31,khi) owns sample ln31 jointly with its khi
// partner; khi selects fragment k-halves, C/D row quadrants, and which
// feature of each pair the lane splines. z[16] is replicated across the
// pair and re-synced with one __shfl_xor per feature-pair.
template<int PAR>
DEV void layer_mfma(int l,
                    const float* __restrict__ scv, const float* __restrict__ shv,
                    const char* __restrict__ ws, char* ldsw,
                    float (&z)[16], float &logdet,
                    int lane, int ln31, int khi)
{
  // ---- hoisted weight-fragment loads ----
  const half8* W1F = (const half8*)(ws + W1F_OFF);
  const half8* W2F = (const half8*)(ws + W2F_OFF);
  half8 w0f = *(const half8*)(ws + W0F_OFF + (l * 64 + lane) * 16);
  half8 w1f[2];
#pragma unroll
  for (int nt = 0; nt < 2; ++nt) w1f[nt] = W1F[(l * 2 + nt) * 64 + lane];
  half8 w2f[8];
#pragma unroll
  for (int kt = 0; kt < 4; ++kt)
#pragma unroll
    for (int nt = 0; nt < 2; ++nt)
      w2f[kt * 2 + nt] = W2F[((l * 4 + kt) * 2 + nt) * 64 + lane];

  // ---- W0 (swapped, K=16): z B-frag comes STRAIGHT from registers ----
  // (own sample's z; khi selects which half of z this lane supplies)
  half8 zf;
  {
    half8 zlo, zhi;
#pragma unroll
    for (int j = 0; j < 8; ++j){ zlo[j] = (f16)z[j]; zhi[j] = (f16)z[8 + j]; }
#pragma unroll
    for (int j = 0; j < 8; ++j) zf[j] = khi ? zhi[j] : zlo[j];
  }
  f32x16 d0t;
  {
    const f32x4* bp = (const f32x4*)(ws + B0T_OFF) + (l * 2 + khi) * 4;
    f32x4 q0 = bp[0], q1 = bp[1], q2 = bp[2], q3 = bp[3];
#pragma unroll
    for (int i = 0; i < 4; ++i){
      d0t[i] = q0[i]; d0t[4 + i] = q1[i]; d0t[8 + i] = q2[i]; d0t[12 + i] = q3[i];
    }
  }
  d0t = __builtin_amdgcn_mfma_f32_32x32x16_f16(w0f, zf, d0t, 0, 0, 0);
  // epilogue: tanh + store rows r = g*8 + 4*khi + j (< 16 for i < 8)
#pragma unroll
  for (int g = 0; g < 2; ++g){
    half4 h4;
#pragma unroll
    for (int j = 0; j < 4; ++j) h4[j] = (f16)ftanh2(d0t[g * 4 + j]);
    *(half4*)(ldsw + H0_OFF + ln31 * H0_STRIDE + g * 16 + khi * 8) = h4;
  }

  // ---- W1 (swapped): D1^T[nt] = W1^T . h0^T ----
  half8 a0 = *(const half8*)(ldsw + H0_OFF + ln31 * H0_STRIDE + khi * 16);
  f32x16 d1t[2];
  {
    const f32x4* B1T = (const f32x4*)(ws + B1T_OFF);
#pragma unroll
    for (int nt = 0; nt < 2; ++nt){
      const f32x4* bp = B1T + ((l * 2 + nt) * 2 + khi) * 4;
      f32x4 q0 = bp[0], q1 = bp[1], q2 = bp[2], q3 = bp[3];
#pragma unroll
      for (int i = 0; i < 4; ++i){
        d1t[nt][i] = q0[i]; d1t[nt][4 + i] = q1[i];
        d1t[nt][8 + i] = q2[i]; d1t[nt][12 + i] = q3[i];
      }
    }
  }
#pragma unroll
  for (int nt = 0; nt < 2; ++nt)
    d1t[nt] = __builtin_amdgcn_mfma_f32_32x32x16_f16(w1f[nt], a0, d1t[nt], 0, 0, 0);
#pragma unroll
  for (int nt = 0; nt < 2; ++nt)
#pragma unroll
    for (int g = 0; g < 4; ++g){
      half4 h4;
#pragma unroll
      for (int j = 0; j < 4; ++j) h4[j] = (f16)ftanh2(d1t[nt][g * 4 + j]);
      *(half4*)(ldsw + H_OFF + ln31 * H_STRIDE + nt * 64 + g * 16 + khi * 8) = h4;
    }

  // ---- W2 (swapped): D2^T[nt] = W2^T . h1^T ----
  half8 a1[4];
#pragma unroll
  for (int kt = 0; kt < 4; ++kt)
    a1[kt] = ld_h8_pair(ldsw + H_OFF + ln31 * H_STRIDE + kt * 32 + khi * 16);
  f32x16 d2t[2];
  {
    const f32x4* B2T = (const f32x4*)(ws + B2T_OFF);
#pragma unroll
    for (int nt = 0; nt < 2; ++nt){
      const f32x4* bp = B2T + ((l * 2 + nt) * 2 + khi) * 4;
      f32x4 q0 = bp[0], q1 = bp[1], q2 = bp[2], q3 = bp[3];
#pragma unroll
      for (int i = 0; i < 4; ++i){
        d2t[nt][i] = q0[i]; d2t[nt][4 + i] = q1[i];
        d2t[nt][8 + i] = q2[i]; d2t[nt][12 + i] = q3[i];
      }
    }
  }
#pragma unroll
  for (int kt = 0; kt < 4; ++kt)
#pragma unroll
    for (int nt = 0; nt < 2; ++nt)
      d2t[nt] = __builtin_amdgcn_mfma_f32_32x32x16_f16(w2f[kt * 2 + nt], a1[kt], d2t[nt], 0, 0, 0);

  // ---- prefetch pair v=0 (features u=0,1) frags + row-biases ----
  const half8* WOF = (const half8*)(ws + WOF_OFF);
  half8 bfnA[4], bfnB[4];
#pragma unroll
  for (int kt = 0; kt < 4; ++kt){
    bfnA[kt] = WOF[((l * 8 + 0) * 4 + kt) * 64 + lane];
    bfnB[kt] = WOF[((l * 8 + 1) * 4 + kt) * 64 + lane];
  }
  float botvA[16], botvB[16];
  load_botv(ws, l, 0, khi, botvA);
  load_botv(ws, l, 1, khi, botvB);

  // epilogue: h2 -> H (no tanh)
#pragma unroll
  for (int nt = 0; nt < 2; ++nt)
#pragma unroll
    for (int g = 0; g < 4; ++g){
      half4 h4;
#pragma unroll
      for (int j = 0; j < 4; ++j) h4[j] = (f16)d2t[nt][g * 4 + j];
      *(half4*)(ldsw + H_OFF + ln31 * H_STRIDE + nt * 64 + g * 16 + khi * 8) = h4;
    }

  // ---- h2 B-fragments (reused across all feature pairs). After these
  //      reads this wave's H0/H bytes are dead -> P may alias them. ----
  half8 a2[4];
#pragma unroll
  for (int kt = 0; kt < 4; ++kt)
    a2[kt] = ld_h8_pair(ldsw + H_OFF + ln31 * H_STRIDE + kt * 32 + khi * 16);

  // ---- feature-pair pipeline (FULLY UNROLLED: z indices must be
  //      compile-time — two dynamic z accesses/iter would demote z to
  //      scratch, the r1 failure). Pair v = features (2v, 2v+1); lane khi
  //      splines feature 2v+khi of its own sample. ----
  wout_pair(a2, bfnA, bfnB, botvA, botvB, ldsw, ln31, khi);
#pragma unroll
  for (int kt = 0; kt < 4; ++kt){
    bfnA[kt] = WOF[((l * 8 + 2) * 4 + kt) * 64 + lane];
    bfnB[kt] = WOF[((l * 8 + 3) * 4 + kt) * 64 + lane];
  }
  load_botv(ws, l, 2, khi, botvA);
  load_botv(ws, l, 3, khi, botvB);

#pragma unroll
  for (int v = 0; v < 4; ++v){
    // read own feature's p: slot khi, 6 x f32x4 + 1 scalar (16B-aligned)
    float p[25];
    {
      const char* pb = ldsw + P_OFF + khi * P_SLOT + ln31 * P_STRIDE;
#pragma unroll
      for (int q = 0; q < 6; ++q){
        f32x4 vq = *(const f32x4*)(pb + q * 16);
#pragma unroll
        for (int i = 0; i < 4; ++i) p[q * 4 + i] = vq[i];
      }
      p[24] = *(const float*)(pb + 96);
    }

    // issue next pair's MFMAs + stores before the spline
    if (v < 3){
      wout_pair(a2, bfnA, bfnB, botvA, botvB, ldsw, ln31, khi);
      if (v < 2){
#pragma unroll
        for (int kt = 0; kt < 4; ++kt){
          bfnA[kt] = WOF[((l * 8 + 2 * v + 4) * 4 + kt) * 64 + lane];
          bfnB[kt] = WOF[((l * 8 + 2 * v + 5) * 4 + kt) * 64 + lane];
        }
        load_botv(ws, l, 2 * v + 4, khi, botvA);
        load_botv(ws, l, 2 * v + 5, khi, botvB);
      }
    }

    const int fA = PAR + 4 * v;        // feature of u=2v   (khi=0 lane)
    const int fB = fA + 2;             // feature of u=2v+1 (khi=1 lane)
    float xv = khi ? z[fB] : z[fA];
    float y, ld;
    rq_spline(p, xv, y, ld);
    float yx = __shfl_xor(y, 32, 64);  // partner's updated feature
    z[fA] = khi ? yx : y;
    z[fB] = khi ? y  : yx;
    logdet += ld;                      // per-lane partial (own features)
  }

  // ---- affine (log|scale| sum precomputed in prep) ----
  const float* scp = scv + l * 16;
  const float* shp = shv + l * 16;
#pragma unroll
  for (int j = 0; j < 16; ++j)
    z[j] = fmaf(z[j], scp[j], shp[j]);
}

extern "C" __global__ void __launch_bounds__(256, 2)
flow_kernel(const float* __restrict__ x,
            const float* __restrict__ scv, const float* __restrict__ shv,
            const char* __restrict__ ws, float* __restrict__ out, int B)
{
  extern __shared__ char lds[];
  const int t    = threadIdx.x;
  const int lane = t & 63;
  const int wv   = t >> 6;
  const int ln31 = lane & 31;
  const int khi  = lane >> 5;
  char* ldsw = lds + wv * ARENA;                 // wave-private arena
  const int g = blockIdx.x * 128 + wv * 32 + ln31;  // khi pair: same sample

  float z[16];
  const float4* xv4 = reinterpret_cast<const float4*>(x + (size_t)g * 16);
  float4 a0 = xv4[0], a1 = xv4[1], a2 = xv4[2], a3 = xv4[3];
  z[0]=a0.x; z[1]=a0.y; z[2]=a0.z; z[3]=a0.w;
  z[4]=a1.x; z[5]=a1.y; z[6]=a1.z; z[7]=a1.w;
  z[8]=a2.x; z[9]=a2.y; z[10]=a2.z; z[11]=a2.w;
  z[12]=a3.x; z[13]=a3.y; z[14]=a3.z; z[15]=a3.w;

  float logdet = 0.f;                 // log2 units, per-lane partial
  for (int l = 7; l >= 0; --l){
    if (l & 1) layer_mfma<1>(l, scv, shv, ws, ldsw, z, logdet, lane, ln31, khi);
    else       layer_mfma<0>(l, scv, shv, ws, ldsw, z, logdet, lane, ln31, khi);
  }

  logdet += __shfl_xor(logdet, 32, 64);  // merge partner's feature partials

  float sumlog = *(const float*)(ws + SUMLOG_OFF);
  float ss = 0.f;
#pragma unroll
  for (int j = 0; j < 16; ++j) ss = fmaf(z[j], z[j], ss);
  if (khi == 0)
    out[g] = fmaf(LN2F, logdet, -0.5f * ss - 14.7030165f + sumlog);
}

extern "C" void kernel_launch(void* const* d_in, const int* in_sizes, int n_in,
                              void* d_out, int out_size, void* d_ws, size_t ws_size,
                              hipStream_t stream)
{
  const float* x    = (const float*)d_in[0];
  const float* W0   = (const float*)d_in[1];
  const float* b0   = (const float*)d_in[2];
  const float* W1   = (const float*)d_in[3];
  const float* b1   = (const float*)d_in[4];
  const float* W2   = (const float*)d_in[5];
  const float* b2   = (const float*)d_in[6];
  const float* Wout = (const float*)d_in[7];
  const float* bout = (const float*)d_in[8];
  const float* scale= (const float*)d_in[9];
  const float* shift= (const float*)d_in[10];

  int B = in_sizes[0] / 16;

  hipLaunchKernelGGL(prep_kernel, dim3(111), dim3(256), 0, stream,
                     W0, b0, W1, b1, W2, b2, Wout, bout, scale, (char*)d_ws);

  hipLaunchKernelGGL(flow_kernel, dim3(B / 128), dim3(256), LDS_BYTES, stream,
                     x, scale, shift,
                     (const char*)d_ws, (float*)d_out, B);
}

// Round 17
// 177.841 us; speedup vs baseline: 1.1029x; 1.1029x over previous
//
#include <hip/hip_runtime.h>
#include <math.h>

typedef _Float16 f16;
typedef _Float16 half4 __attribute__((ext_vector_type(4)));
typedef _Float16 half8 __attribute__((ext_vector_type(8)));
typedef float f32x4  __attribute__((ext_vector_type(4)));
typedef float f32x16 __attribute__((ext_vector_type(16)));

#define DEV __device__ __forceinline__

// ---------------- workspace layout (bytes) ----------------
#define W1F_OFF 0        // [L][nt2]      : 16 frags  = 16 KB   (x 2*log2e)
#define W2F_OFF 16384    // [L][kt4][nt2] : 64 frags  = 64 KB   (unscaled)
#define WOF_OFF 81920    // [L][u8][kt4]  : 256 frags = 256 KB  (x log2e)
#define B1T_OFF 344064   // [L][nt2][khi2][16] f32 b1 ROW-vec (x 2*log2e) = 2 KB
#define B2T_OFF 346112   // [L][nt2][khi2][16] f32 b2 ROW-vec (unscaled)  = 2 KB
#define SUMLOG_OFF 352256 // 1 fp32: sum over all layers/features of log|scale|
#define W0F_OFF 352320   // [L][64] half8 A-frags of W0^T (mask-zeroed, x 2*log2e) = 8 KB
#define B0T_OFF 361088   // [L][khi2][16] f32 b0 ROW-vec (x 2*log2e) = 1 KB
#define BOT_OFF 363136   // [L][u8][khi2][16] f32 bout ROW-vec (x log2e, offset folded) = 8 KB

// ---------------- LDS: PER-WAVE ARENA (12800 B), 4 waves/block -------------
// r13 champion layout. 64 samples/wave, 1 lane/sample.
// (2-lane-per-sample splits measured slower 3x — r1-r3, r15. Do not re-split.)
// All regions of a wave's arena lie in [wv*ARENA,(wv+1)*ARENA) — genuinely
// wave-private. Within one wave DS ops execute in program order, so P may
// alias H0+H: the a2 register reads (last H use) precede all P stores; the
// next layer's Z/H0 writes follow this layer's last P read (u=7).
// Bank design: H_STRIDE=152 (38 dwords) keeps b64 epilogue stores 2-way
// (free); P f32x4 at stride 112 is 2-way (free); h0 b64 at stride 48 is
// <=4-way (bounded). Do NOT raise __launch_bounds__ waves/EU above 2:
// (256,4) r1/r2 and (256,3) r9 spilled f32x16 blocks (60-500 MB scratch).
//   H0 : [64][48]  f16 z/h0 staging   @ arena+0     (3072)
//   H  : [64][152] f16 h1/h2 staging  @ arena+3072  (9728, ends 12800)
//   P  : [64][112] f32 spline params  @ arena+0     (7168, aliases H0+H)
#define H0_OFF    0
#define H0_STRIDE 48
#define H_OFF     3072
#define H_STRIDE  152
#define P_OFF     0
#define P_STRIDE  112
#define ARENA     12800
#define LDS_BYTES (4 * ARENA)

DEV float frcp(float x){ return __builtin_amdgcn_rcpf(x); }

#if __has_builtin(__builtin_amdgcn_exp2f)
DEV float fexp2(float x){ return __builtin_amdgcn_exp2f(x); }
#else
DEV float fexp2(float x){ return exp2f(x); }
#endif
#if __has_builtin(__builtin_amdgcn_logf)
DEV float flog2(float x){ return __builtin_amdgcn_logf(x); }
#else
DEV float flog2(float x){ return log2f(x); }
#endif

#define LN2F    0.69314718056f
#define LOG2EF  1.4426950409f
#define TWOLOG2EF 2.8853900818f

// tanh with PRE-SCALED input: x' = 2*log2e * x_linear.
// tanh = 1 - 2/(2^{x'}+1). Robust without clamp. 4 instructions.
DEV float ftanh2(float x){
  float e = fexp2(x);
  float r = frcp(e + 1.f);
  return fmaf(-2.f, r, 1.f);
}

// depth-3 8-way select driven by shared masks (m4,m2,m1): picks
// v[4*m4 + 2*m2 + m1].
DEV float sel8(float v0, float v1, float v2, float v3,
               float v4, float v5, float v6, float v7,
               bool m4, bool m2, bool m1)
{
  float a0 = m4 ? v4 : v0;
  float a1 = m4 ? v5 : v1;
  float a2 = m4 ? v6 : v2;
  float a3 = m4 ? v7 : v3;
  float c0 = m2 ? a2 : a0;
  float c1 = m2 ? a3 : a1;
  return m1 ? c1 : c0;
}

// Rational-quadratic spline forward + log-det (fp32, per-thread).
// p in LOG2 DOMAIN (params x log2e, softplus offset pre-folded at prep).
// ld_out in LOG2 units.
// DEPTH-REDUCED (r17): tree prefix sums replace the 8-deep cumsum; all six
// 7-deep select chains use a shared 3-level bit-select tree. Masks verified
// by enumeration over all 8 monotone b-patterns: m4=b4; m2=m4?b6:b2;
// m1=m4?(m2?b7:b5):(m2?b3:b1) reproduce the bits of idx. (r16's bug: the
// m1 ternary had m2/m4 swapped -> wrong bin for idx in {2,3,4,5}.)
DEV void rq_spline(const float p[25], float xv, float &y_out, float &ld_out)
{
  float ew[8], eh[8];
#pragma unroll
  for (int k = 0; k < 8; ++k) ew[k] = fexp2(p[k]);
#pragma unroll
  for (int k = 0; k < 8; ++k) eh[k] = fexp2(p[8 + k]);

  // tree sums + prefixes (w)
  float s01 = ew[0] + ew[1], s23 = ew[2] + ew[3];
  float s45 = ew[4] + ew[5], s67 = ew[6] + ew[7];
  float s03 = s01 + s23, s47 = s45 + s67;
  float rw = frcp(s03 + s47) * 19.9992f;    // (RMAX-RMIN) - K*MIN_BIN
  float c1 = ew[0], c2 = s01, c3 = s01 + ew[2], c4 = s03;
  float c5 = s03 + ew[4], c6 = s03 + s45, c7 = c6 + ew[6];

  // tree sums + prefixes (h)
  float t01 = eh[0] + eh[1], t23 = eh[2] + eh[3];
  float t45 = eh[4] + eh[5], t67 = eh[6] + eh[7];
  float t03 = t01 + t23, t47 = t45 + t67;
  float rh = frcp(t03 + t47) * 19.9992f;
  float d1 = eh[0], d2 = t01, d3 = t01 + eh[2], d4 = t03;
  float d5 = t03 + eh[4], d6 = t03 + t45, d7 = d6 + eh[6];

  // knot x-positions (independent fmas; xpos_j = cj*rw + (-10 + j*1e-4))
  float x1 = fmaf(c1, rw, -10.f + 1e-4f);
  float x2 = fmaf(c2, rw, -10.f + 2e-4f);
  float x3 = fmaf(c3, rw, -10.f + 3e-4f);
  float x4 = fmaf(c4, rw, -10.f + 4e-4f);
  float x5 = fmaf(c5, rw, -10.f + 5e-4f);
  float x6 = fmaf(c6, rw, -10.f + 6e-4f);
  float x7 = fmaf(c7, rw, -10.f + 7e-4f);

  bool b1 = xv >= x1, b2 = xv >= x2, b3 = xv >= x3, b4 = xv >= x4;
  bool b5 = xv >= x5, b6 = xv >= x6, b7 = xv >= x7;
  // shared selector masks = bits of idx (binary search over monotone b)
  bool m4 = b4;
  bool m2 = m4 ? b6 : b2;
  bool m1 = m4 ? (m2 ? b7 : b5) : (m2 ? b3 : b1);

  float xk   = sel8(-10.f, x1, x2, x3, x4, x5, x6, x7, m4, m2, m1);
  float ewk  = sel8(ew[0], ew[1], ew[2], ew[3], ew[4], ew[5], ew[6], ew[7], m4, m2, m1);
  float ehk  = sel8(eh[0], eh[1], eh[2], eh[3], eh[4], eh[5], eh[6], eh[7], m4, m2, m1);
  float Ssel = sel8(0.f, d1, d2, d3, d4, d5, d6, d7, m4, m2, m1);
  float ycst = sel8(-10.f, -10.f + 1e-4f, -10.f + 2e-4f, -10.f + 3e-4f,
                    -10.f + 4e-4f, -10.f + 5e-4f, -10.f + 6e-4f, -10.f + 7e-4f,
                    m4, m2, m1);
  float vA   = sel8(p[16], p[17], p[18], p[19], p[20], p[21], p[22], p[23], m4, m2, m1);
  float vB   = sel8(p[17], p[18], p[19], p[20], p[21], p[22], p[23], p[24], m4, m2, m1);

  float bw = fmaf(ewk, rw, 1e-4f);
  float yk = fmaf(Ssel, rh, ycst);
  float bh = fmaf(ehk, rh, 1e-4f);

  // softplus in log2 domain: ln(1+e^u) = ln2*(max(v,0)+log2(1+2^{-|v|}))
  float tA = fmaxf(vA, 0.f) + flog2(1.f + fexp2(-fabsf(vA)));
  float dk  = fmaf(LN2F, tA, 1e-4f);
  float tB = fmaxf(vB, 0.f) + flog2(1.f + fexp2(-fabsf(vB)));
  float dk1 = fmaf(LN2F, tB, 1e-4f);

  float rbw = frcp(bw);
  float s   = bh * rbw;
  float zf  = fminf(fmaxf((xv - xk) * rbw, 0.f), 1.f);
  float z1  = 1.f - zf;
  float zz  = zf * zf, z01 = zf * z1;
  float den = s + (dk1 + dk - 2.f * s) * z01;
  float rden = frcp(den);
  float yv  = yk + bh * (s * zz + dk * z01) * rden;
  float num = dk1 * zz + 2.f * s * z01 + dk * z1 * z1;
  float ldv2 = flog2(s * s * num * rden * rden);   // log2-domain

  bool outside = (xv <= -10.f) || (xv >= 10.f);
  y_out  = outside ? xv : yv;
  ld_out = outside ? 0.f : ldv2;
}

// ---------------- prep kernel: pack fp16 fragments into ws ----------------
// (byte-identical to r13 — all fragment formats unchanged)
extern "C" __global__ void __launch_bounds__(256)
prep_kernel(const float* __restrict__ W0, const float* __restrict__ b0,
            const float* __restrict__ W1, const float* __restrict__ b1,
            const float* __restrict__ W2, const float* __restrict__ b2,
            const float* __restrict__ Wo, const float* __restrict__ bout,
            const float* __restrict__ scale, char* __restrict__ ws)
{
  int tid = blockIdx.x * 256 + threadIdx.x;
  if (tid < 1024){                       // W1 frags: [L][nt2]  (x 2*log2e)
    int fi = tid >> 6, lane = tid & 63;
    int l = fi >> 1, nt = fi & 1;
    int n = nt * 32 + (lane & 31), khi = lane >> 5;
    half8 h;
#pragma unroll
    for (int j = 0; j < 8; ++j){ int k = khi * 8 + j; h[j] = (f16)(W1[l * 1024 + k * 64 + n] * TWOLOG2EF); }
    *(half8*)(ws + W1F_OFF + fi * 1024 + lane * 16) = h;
  } else if (tid < 5120){                // W2 frags: [L][kt4][nt2] (unscaled)
    int idx = tid - 1024;
    int fi = idx >> 6, lane = idx & 63;
    int l = fi >> 3, kt = (fi >> 1) & 3, nt = fi & 1;
    int n = nt * 32 + (lane & 31), khi = lane >> 5;
    half8 h;
#pragma unroll
    for (int j = 0; j < 8; ++j){ int k = kt * 16 + khi * 8 + j; h[j] = (f16)W2[l * 4096 + k * 64 + n]; }
    *(half8*)(ws + W2F_OFF + fi * 1024 + lane * 16) = h;
  } else if (tid < 21504){               // Wout used-col frags: [L][u8][kt4] (x log2e)
    int idx = tid - 5120;
    int fi = idx >> 6, lane = idx & 63;
    int l = fi >> 5, u = (fi >> 2) & 7, kt = fi & 3;
    int f = (l & 1) + 2 * u;
    int c = lane & 31, khi = lane >> 5;
    half8 h;
#pragma unroll
    for (int j = 0; j < 8; ++j){
      int k = kt * 16 + khi * 8 + j;
      float v = (c < 25) ? Wo[l * 25600 + k * 400 + f * 25 + c] * LOG2EF : 0.f;
      h[j] = (f16)v;
    }
    *(half8*)(ws + WOF_OFF + fi * 1024 + lane * 16) = h;
  } else if (tid < 22016){               // B1T row-bias: 512 floats (x 2*log2e)
    int idx = tid - 21504;               // = ((l*2+nt)*2+kh)*16 + i
    int l = idx >> 6, nt = (idx >> 5) & 1, kh = (idx >> 4) & 1, i = idx & 15;
    int r = (i & 3) + 8 * (i >> 2) + 4 * kh;
    ((float*)(ws + B1T_OFF))[idx] = b1[l * 64 + nt * 32 + r] * TWOLOG2EF;
  } else if (tid < 22528){               // B2T row-bias: 512 floats (unscaled)
    int idx = tid - 22016;
    int l = idx >> 6, nt = (idx >> 5) & 1, kh = (idx >> 4) & 1, i = idx & 15;
    int r = (i & 3) + 8 * (i >> 2) + 4 * kh;
    ((float*)(ws + B2T_OFF))[idx] = b2[l * 64 + nt * 32 + r];
  } else if (tid == 23552){              // sum of log|scale| over all layers
    float acc = 0.f;
    for (int i = 0; i < 128; ++i) acc += logf(fabsf(scale[i]));
    *(float*)(ws + SUMLOG_OFF) = acc;
  } else if (tid > 23552 && tid < 24065){ // W0F frags: [L], 512 threads
    int idx = tid - 23553;               // = l*64 + lane
    int l = idx >> 6, lane = idx & 63;
    int n = lane & 31, kh5 = lane >> 5;
    half8 h;
#pragma unroll
    for (int j = 0; j < 8; ++j){
      int k = kh5 * 8 + j;
      float v = 0.f;
      if (n < 16 && (((k + l) & 1) == 1))
        v = W0[l * 256 + k * 16 + n] * TWOLOG2EF;
      h[j] = (f16)v;
    }
    *(half8*)(ws + W0F_OFF + idx * 16) = h;
  } else if (tid >= 24065 && tid < 24321){ // B0T row-bias: 256 floats
    int idx = tid - 24065;               // = (l*2+kh)*16 + i
    int l = idx >> 5, kh = (idx >> 4) & 1, i = idx & 15;
    int r = (i & 3) + 8 * (i >> 2) + 4 * kh;
    float v = (r < 16) ? b0[l * 16 + r] * TWOLOG2EF : 0.f;
    ((float*)(ws + B0T_OFF))[idx] = v;
  } else if (tid >= 26241 && tid < 28289){ // BOT row-bias: 2048 floats
    int idx = tid - 26241;               // = l*256 + u*32 + khi*16 + i
    int l = idx >> 8, u = (idx >> 5) & 7, kh = (idx >> 4) & 1, i = idx & 15;
    int f = (l & 1) + 2 * u;
    int r = (i & 3) + 8 * (i >> 2) + 4 * kh;
    float v = 0.f;
    if (r < 25){
      v = bout[l * 400 + f * 25 + r];
      if (r >= 16) v += 0.54116666f;     // softplus offset folded
      v *= LOG2EF;
    }
    ((float*)(ws + BOT_OFF))[idx] = v;
  }
}

// ---- load a 16-float row-bias vector (BOT layout) ----
DEV void load_botv(const char* __restrict__ ws, int l, int u, int khi,
                   float (&botv)[16])
{
  const f32x4* bp = (const f32x4*)(ws + BOT_OFF) + ((l * 8 + u) * 2 + khi) * 4;
  f32x4 q0 = bp[0], q1 = bp[1], q2 = bp[2], q3 = bp[3];
#pragma unroll
  for (int i = 0; i < 4; ++i){
    botv[i] = q0[i]; botv[4 + i] = q1[i]; botv[8 + i] = q2[i]; botv[12 + i] = q3[i];
  }
}

// ---- H b128-equivalent load split into two b64s (stride 152 rows are only
//      8B-aligned; b64 at 38-dword stride is 2-way = free). ----
DEV half8 ld_h8_pair(const char* p)
{
  half4 lo = *(const half4*)(p);
  half4 hi = *(const half4*)(p + 8);
  half8 r;
#pragma unroll
  for (int i = 0; i < 4; ++i){ r[i] = lo[i]; r[4 + i] = hi[i]; }
  return r;
}

// ---- one Wout feature: SWAPPED MFMA (D^T = Wout^T . h2^T) + f32x4 P-store -
DEV void wout_feature(const half8 (&a2)[2][4], const half8 (&bfn)[4],
                      const float (&botv)[16], char* ldsw, int ln31, int khi)
{
  f32x16 dp[2];
#pragma unroll
  for (int mt = 0; mt < 2; ++mt)
#pragma unroll
    for (int i = 0; i < 16; ++i) dp[mt][i] = botv[i];
#pragma unroll
  for (int kt = 0; kt < 4; ++kt)
#pragma unroll
    for (int mt = 0; mt < 2; ++mt)
      dp[mt] = __builtin_amdgcn_mfma_f32_32x32x16_f16(bfn[kt], a2[mt][kt], dp[mt], 0, 0, 0);
#pragma unroll
  for (int mt = 0; mt < 2; ++mt){
    int s = mt * 32 + ln31;                        // wave-local sample row
    char* base = ldsw + P_OFF + s * P_STRIDE + khi * 16;  // 16B-aligned
    f32x4 c0, c1, c2;
#pragma unroll
    for (int i = 0; i < 4; ++i){
      c0[i] = dp[mt][i];       // params r = 4*khi + 0..3
      c1[i] = dp[mt][4 + i];   // params r = 4*khi + 8..11
      c2[i] = dp[mt][8 + i];   // params r = 4*khi + 16..19
    }
    *(f32x4*)(base)      = c0;
    *(f32x4*)(base + 32) = c1;
    *(f32x4*)(base + 64) = c2;
    if (khi == 0)                                  // r = 24 (khi=1 -> 28, skip)
      *(float*)(base + 96) = dp[mt][12];
  }
}

// ---------------- one coupling layer (arena = wave-private LDS) ------------
// 64 samples/wave, 1 lane/sample. ALL FOUR GEMMs (W0,W1,W2,Wout) use the
// swapped MFMA (D^T = W^T . h^T); outputs land sample-major.
template<int PAR>
DEV void layer_mfma(int l,
                    const float* __restrict__ scv, const float* __restrict__ shv,
                    const char* __restrict__ ws, char* ldsw,
                    float (&z)[16], float &logdet,
                    int lane, int ln31, int khi)
{
  // ---- hoisted weight-fragment loads (latency hidden behind staging) ----
  const half8* W1F = (const half8*)(ws + W1F_OFF);
  const half8* W2F = (const half8*)(ws + W2F_OFF);
  half8 w0f = *(const half8*)(ws + W0F_OFF + (l * 64 + lane) * 16);
  half8 w1f[2];
#pragma unroll
  for (int nt = 0; nt < 2; ++nt) w1f[nt] = W1F[(l * 2 + nt) * 64 + lane];
  half8 w2f[8];
#pragma unroll
  for (int kt = 0; kt < 4; ++kt)
#pragma unroll
    for (int nt = 0; nt < 2; ++nt)
      w2f[kt * 2 + nt] = W2F[((l * 4 + kt) * 2 + nt) * 64 + lane];

  // ---- W0 (swapped, K=16): stage z as f16, D0^T = W0^T . z^T ----
  {
    half8 zlo, zhi;
#pragma unroll
    for (int j = 0; j < 8; ++j){ zlo[j] = (f16)z[j]; zhi[j] = (f16)z[8 + j]; }
    *(half8*)(ldsw + H0_OFF + lane * H0_STRIDE)      = zlo;
    *(half8*)(ldsw + H0_OFF + lane * H0_STRIDE + 16) = zhi;
  }
  f32x16 d0t[2];
  {
    const f32x4* bp = (const f32x4*)(ws + B0T_OFF) + (l * 2 + khi) * 4;
    f32x4 q0 = bp[0], q1 = bp[1], q2 = bp[2], q3 = bp[3];
#pragma unroll
    for (int mt = 0; mt < 2; ++mt)
#pragma unroll
      for (int i = 0; i < 4; ++i){
        d0t[mt][i] = q0[i]; d0t[mt][4 + i] = q1[i];
        d0t[mt][8 + i] = q2[i]; d0t[mt][12 + i] = q3[i];
      }
  }
  {
    half8 zf[2];
#pragma unroll
    for (int mt = 0; mt < 2; ++mt)
      zf[mt] = *(const half8*)(ldsw + H0_OFF + (mt * 32 + ln31) * H0_STRIDE + khi * 16);
#pragma unroll
    for (int mt = 0; mt < 2; ++mt)
      d0t[mt] = __builtin_amdgcn_mfma_f32_32x32x16_f16(w0f, zf[mt], d0t[mt], 0, 0, 0);
  }
  // epilogue: tanh + store meaningful rows (i<8 -> r = g*8 + 4*khi + j < 16)
#pragma unroll
  for (int mt = 0; mt < 2; ++mt){
    int s = mt * 32 + ln31;
#pragma unroll
    for (int g = 0; g < 2; ++g){
      half4 h4;
#pragma unroll
      for (int j = 0; j < 4; ++j) h4[j] = (f16)ftanh2(d0t[mt][g * 4 + j]);
      *(half4*)(ldsw + H0_OFF + s * H0_STRIDE + g * 16 + khi * 8) = h4;
    }
  }

  // ---- W1 (swapped): D1^T[nt][mt] = W1^T . h0^T, bias row-vector init ----
  half8 a0[2];
#pragma unroll
  for (int mt = 0; mt < 2; ++mt)
    a0[mt] = *(const half8*)(ldsw + H0_OFF + (mt * 32 + ln31) * H0_STRIDE + khi * 16);
  f32x16 d1t[2][2];
  {
    const f32x4* B1T = (const f32x4*)(ws + B1T_OFF);
#pragma unroll
    for (int nt = 0; nt < 2; ++nt){
      const f32x4* bp = B1T + ((l * 2 + nt) * 2 + khi) * 4;
      f32x4 q0 = bp[0], q1 = bp[1], q2 = bp[2], q3 = bp[3];
#pragma unroll
      for (int mt = 0; mt < 2; ++mt)
#pragma unroll
        for (int i = 0; i < 4; ++i){
          d1t[nt][mt][i] = q0[i]; d1t[nt][mt][4 + i] = q1[i];
          d1t[nt][mt][8 + i] = q2[i]; d1t[nt][mt][12 + i] = q3[i];
        }
    }
  }
#pragma unroll
  for (int nt = 0; nt < 2; ++nt)
#pragma unroll
    for (int mt = 0; mt < 2; ++mt)
      d1t[nt][mt] = __builtin_amdgcn_mfma_f32_32x32x16_f16(w1f[nt], a0[mt], d1t[nt][mt], 0, 0, 0);
  // epilogue: tanh + pack 4 consecutive f16 -> b64 store (n = nt*32+8g+j+4khi)
#pragma unroll
  for (int nt = 0; nt < 2; ++nt)
#pragma unroll
    for (int mt = 0; mt < 2; ++mt){
      int s = mt * 32 + ln31;
#pragma unroll
      for (int g = 0; g < 4; ++g){
        half4 h4;
#pragma unroll
        for (int j = 0; j < 4; ++j) h4[j] = (f16)ftanh2(d1t[nt][mt][g * 4 + j]);
        *(half4*)(ldsw + H_OFF + s * H_STRIDE + nt * 64 + g * 16 + khi * 8) = h4;
      }
    }

  // ---- W2 (swapped): D2^T[nt][mt] = W2^T . h1^T ----
  half8 a1[2][4];
#pragma unroll
  for (int mt = 0; mt < 2; ++mt)
#pragma unroll
    for (int kt = 0; kt < 4; ++kt)
      a1[mt][kt] = ld_h8_pair(ldsw + H_OFF + (mt * 32 + ln31) * H_STRIDE + kt * 32 + khi * 16);
  f32x16 d2t[2][2];
  {
    const f32x4* B2T = (const f32x4*)(ws + B2T_OFF);
#pragma unroll
    for (int nt = 0; nt < 2; ++nt){
      const f32x4* bp = B2T + ((l * 2 + nt) * 2 + khi) * 4;
      f32x4 q0 = bp[0], q1 = bp[1], q2 = bp[2], q3 = bp[3];
#pragma unroll
      for (int mt = 0; mt < 2; ++mt)
#pragma unroll
        for (int i = 0; i < 4; ++i){
          d2t[nt][mt][i] = q0[i]; d2t[nt][mt][4 + i] = q1[i];
          d2t[nt][mt][8 + i] = q2[i]; d2t[nt][mt][12 + i] = q3[i];
        }
    }
  }
#pragma unroll
  for (int kt = 0; kt < 4; ++kt)
#pragma unroll
    for (int nt = 0; nt < 2; ++nt)
#pragma unroll
      for (int mt = 0; mt < 2; ++mt)
        d2t[nt][mt] = __builtin_amdgcn_mfma_f32_32x32x16_f16(w2f[kt * 2 + nt], a1[mt][kt], d2t[nt][mt], 0, 0, 0);

  // ---- prefetch feature u=0's Wout frags + row-bias (hidden behind epi) ----
  const half8* WOF = (const half8*)(ws + WOF_OFF);
  half8 bfn[4];
#pragma unroll
  for (int kt = 0; kt < 4; ++kt) bfn[kt] = WOF[((l * 8 + 0) * 4 + kt) * 64 + lane];
  float botv[16];
  load_botv(ws, l, 0, khi, botv);

  // epilogue: pack 4 consecutive f16 -> b64 store (no tanh)
#pragma unroll
  for (int nt = 0; nt < 2; ++nt)
#pragma unroll
    for (int mt = 0; mt < 2; ++mt){
      int s = mt * 32 + ln31;
#pragma unroll
      for (int g = 0; g < 4; ++g){
        half4 h4;
#pragma unroll
        for (int j = 0; j < 4; ++j) h4[j] = (f16)d2t[nt][mt][g * 4 + j];
        *(half4*)(ldsw + H_OFF + s * H_STRIDE + nt * 64 + g * 16 + khi * 8) = h4;
      }
    }

  // ---- h2 B-fragments (reused across all 8 features). After these reads
  //      this wave's H0/H bytes are dead -> P (arena+0) may alias them. ----
  half8 a2[2][4];
#pragma unroll
  for (int mt = 0; mt < 2; ++mt)
#pragma unroll
    for (int kt = 0; kt < 4; ++kt)
      a2[mt][kt] = ld_h8_pair(ldsw + H_OFF + (mt * 32 + ln31) * H_STRIDE + kt * 32 + khi * 16);

  // ---- feature-loop software pipeline (r8 schedule, arena P) ----
  // p_{u+1} MFMA + store issued BEFORE spline(u); per-wave DS program order
  // makes the single P slot safe (reads of p_u precede stores of p_{u+1}).
  wout_feature(a2, bfn, botv, ldsw, ln31, khi);
#pragma unroll
  for (int kt = 0; kt < 4; ++kt) bfn[kt] = WOF[((l * 8 + 1) * 4 + kt) * 64 + lane];
  load_botv(ws, l, 1, khi, botv);

#pragma unroll 1
  for (int u = 0; u < 8; ++u){
    // read own sample's p for feature u: 6 x f32x4 + 1 scalar (16B-aligned)
    float p[25];
    {
      const char* pb = ldsw + P_OFF + lane * P_STRIDE;
#pragma unroll
      for (int q = 0; q < 6; ++q){
        f32x4 v = *(const f32x4*)(pb + q * 16);
#pragma unroll
        for (int i = 0; i < 4; ++i) p[q * 4 + i] = v[i];
      }
      p[24] = *(const float*)(pb + 96);
    }

    // issue next feature's MFMA + store before the spline
    if (u < 7){
      wout_feature(a2, bfn, botv, ldsw, ln31, khi);
      if (u < 6){
#pragma unroll
        for (int kt = 0; kt < 4; ++kt) bfn[kt] = WOF[((l * 8 + u + 2) * 4 + kt) * 64 + lane];
        load_botv(ws, l, u + 2, khi, botv);
      }
    }

    const int f = PAR + 2 * u;
    float y, ld;
    rq_spline(p, z[f], y, ld);
    z[f] = y;
    logdet += ld;                       // log2-domain accumulation
  }

  // ---- affine (log|scale| sum precomputed in prep) ----
  const float* scp = scv + l * 16;
  const float* shp = shv + l * 16;
#pragma unroll
  for (int j = 0; j < 16; ++j)
    z[j] = fmaf(z[j], scp[j], shp[j]);
}

extern "C" __global__ void __launch_bounds__(256, 2)
flow_kernel(const float* __restrict__ x,
            const float* __restrict__ scv, const float* __restrict__ shv,
            const char* __restrict__ ws, float* __restrict__ out, int B)
{
  extern __shared__ char lds[];
  const int t    = threadIdx.x;
  const int lane = t & 63;
  const int wv   = t >> 6;
  const int ln31 = lane & 31;
  const int khi  = lane >> 5;
  char* ldsw = lds + wv * ARENA;        // wave-private arena
  const int g = blockIdx.x * 256 + t;

  float z[16];
  const float4* xv = reinterpret_cast<const float4*>(x + (size_t)g * 16);
  float4 a0 = xv[0], a1 = xv[1], a2 = xv[2], a3 = xv[3];
  z[0]=a0.x; z[1]=a0.y; z[2]=a0.z; z[3]=a0.w;
  z[4]=a1.x; z[5]=a1.y; z[6]=a1.z; z[7]=a1.w;
  z[8]=a2.x; z[9]=a2.y; z[10]=a2.z; z[11]=a2.w;
  z[12]=a3.x; z[13]=a3.y; z[14]=a3.z; z[15]=a3.w;

  float logdet = 0.f;                 // in log2 units
  for (int l = 7; l >= 0; --l){
    if (l & 1) layer_mfma<1>(l, scv, shv, ws, ldsw, z, logdet, lane, ln31, khi);
    else       layer_mfma<0>(l, scv, shv, ws, ldsw, z, logdet, lane, ln31, khi);
  }

  float sumlog = *(const float*)(ws + SUMLOG_OFF);
  float ss = 0.f;
#pragma unroll
  for (int j = 0; j < 16; ++j) ss = fmaf(z[j], z[j], ss);
  out[g] = fmaf(LN2F, logdet, -0.5f * ss - 14.7030165f + sumlog);
}

extern "C" void kernel_launch(void* const* d_in, const int* in_sizes, int n_in,
                              void* d_out, int out_size, void* d_ws, size_t ws_size,
                              hipStream_t stream)
{
  const float* x    = (const float*)d_in[0];
  const float* W0   = (const float*)d_in[1];
  const float* b0   = (const float*)d_in[2];
  const float* W1   = (const float*)d_in[3];
  const float* b1   = (const float*)d_in[4];
  const float* W2   = (const float*)d_in[5];
  const float* b2   = (const float*)d_in[6];
  const float* Wout = (const float*)d_in[7];
  const float* bout = (const float*)d_in[8];
  const float* scale= (const float*)d_in[9];
  const float* shift= (const float*)d_in[10];

  int B = in_sizes[0] / 16;

  hipLaunchKernelGGL(prep_kernel, dim3(111), dim3(256), 0, stream,
                     W0, b0, W1, b1, W2, b2, Wout, bout, scale, (char*)d_ws);

  hipLaunchKernelGGL(flow_kernel, dim3(B / 256), dim3(256), LDS_BYTES, stream,
                     x, scale, shift,
                     (const char*)d_ws, (float*)d_out, B);
}